// Round 6
// baseline (711.805 us; speedup 1.0000x reference)
//
#include <hip/hip_runtime.h>
#include <hip/hip_bf16.h>
#include <math.h>

// MoE top-2/8, T=4096, d=1024, ffn=3584. fp32 in/out, bf16 MFMA internally.
// R9: attack the ~365us of non-GEMM time (R8 budget: gemm1 153 + gemm2 ~125
// vs total 644). (a) gate writes Xb (drops cvt-x). (b) route fused with
// W1/W3 cvt in one dispatch: block 0 routes, blocks 1..2048 convert -- the
// single-block route hides under 352MB of BW-bound cvt. (c) tiered ws: if
// >=250MB, W2b gets its own region and W2 cvt runs as blockIdx.z==8 blocks
// inside gemm1 (overlapped); else separate cvt after gemm1 (192MB tier).
// (d) GEMM K-loops: single-barrier 2-phase (catalog T3-min recipe):
// STAGE(next)->ds_read cur->MFMA->vmcnt(0)->barrier. One barrier/step.
// R8 post-mortem: counted vmcnt depth-1 was ~null (+3%); structure is at the
// m97 ceiling; the lever now is overhead, not the inner loop.

#define NUM_EXPERTS 8
#define TOPK 2
#define D_MODEL 1024
#define D_MLP 3584
#define T_TOKENS 4096
#define NSLOT (T_TOKENS * TOPK)
#define SLOT_CAP 9216  // 8192 + 8*128 worst-case padding

#define BM 128
#define BN 128
#define BK 32
#define LDT 40  // LDS row pitch for fallback reg-staged kernels (32 + 8 pad)

typedef __attribute__((ext_vector_type(8))) short bf16x8;
typedef __attribute__((ext_vector_type(4))) float f32x4;

// ---- workspace layout ----
// [0, 147456)                small buffers (top_idx/top_w/hdr/slots)
// [147456, +66,060,288)      H bf16 [SLOT_CAP][D_MLP]
// Xb  bf16 [T][D_MODEL]      8,388,608 B
// W1b bf16 [E][D_MLP][D]    58,720,256 B
// W3b bf16 [E][D_MLP][D]    58,720,256 B  (Y fp32 37.7MB overlays after gemm1)
// W2b (big tier only)       58,720,256 B  (mid tier: W2b overlays W1b)
#define WS_SMALL 147456
#define H_BYTES ((size_t)SLOT_CAP * D_MLP * 2)
#define XB_OFF (WS_SMALL + H_BYTES)
#define XB_BYTES ((size_t)T_TOKENS * D_MODEL * 2)
#define W1B_OFF (XB_OFF + XB_BYTES)
#define W13_BYTES ((size_t)NUM_EXPERTS * (size_t)D_MLP * D_MODEL * 2)
#define W3B_OFF (W1B_OFF + W13_BYTES)
#define WS_FULL (W3B_OFF + W13_BYTES)          // 192,036,864 (granted, ran R4-R8)
#define W2B_OFF WS_FULL
#define WS_BIG (W2B_OFF + W13_BYTES)           // 250,757,120 (tier-gated)
#define WS_NEEDED_OLD (WS_SMALL + H_BYTES)     // 66,207,744

#define NW8 (NUM_EXPERTS * D_MLP * D_MODEL / 8)  // 3,670,016 chunks of 8

__device__ inline unsigned short f32_to_bf16(float f) {
  union { float f; unsigned int u; } v; v.f = f;
  unsigned int u = v.u;
  unsigned int r = (u + 0x7FFFu + ((u >> 16) & 1u)) >> 16;  // RNE
  return (unsigned short)r;
}

__device__ inline bf16x8 pack8(float4 a, float4 b) {
  bf16x8 v;
  v[0] = (short)f32_to_bf16(a.x); v[1] = (short)f32_to_bf16(a.y);
  v[2] = (short)f32_to_bf16(a.z); v[3] = (short)f32_to_bf16(a.w);
  v[4] = (short)f32_to_bf16(b.x); v[5] = (short)f32_to_bf16(b.y);
  v[6] = (short)f32_to_bf16(b.z); v[7] = (short)f32_to_bf16(b.w);
  return v;
}

__device__ __forceinline__ void gload16(const void* g, void* l) {
  __builtin_amdgcn_global_load_lds(
      (__attribute__((address_space(1))) void*)g,
      (__attribute__((address_space(3))) void*)l, 16, 0, 0);
}

// ---------------- zero d_out (fallback path only) ----------------
__global__ void zero_kernel(float4* __restrict__ p, int n4) {
  int i = blockIdx.x * blockDim.x + threadIdx.x;
  if (i < n4) p[i] = make_float4(0.f, 0.f, 0.f, 0.f);
}

// ---------------- fp32 -> bf16 streaming convert (mid-tier W2) -------------
__global__ __launch_bounds__(256) void cvt_kernel(const float* __restrict__ src,
                                                  unsigned short* __restrict__ dst,
                                                  int n8) {
  int i = blockIdx.x * blockDim.x + threadIdx.x;
  const int stride = gridDim.x * blockDim.x;
  for (; i < n8; i += stride) {
    const float4* s = (const float4*)(src + (size_t)i * 8);
    float4 a = s[0], b = s[1];
    *(bf16x8*)(dst + (size_t)i * 8) = pack8(a, b);
  }
}

// ---------------- gating: one wave per token; also writes Xb ----------------
__global__ __launch_bounds__(64) void gate_kernel(const float* __restrict__ x,
                            const float* __restrict__ Wg,
                            int* __restrict__ top_idx,
                            float* __restrict__ top_w,
                            unsigned short* __restrict__ Xb) {
  const int t = blockIdx.x;
  const int lane = threadIdx.x;  // 64 threads
  const float* xr = x + (size_t)t * D_MODEL;

  float xs[16];
#pragma unroll
  for (int i = 0; i < 16; ++i) xs[i] = xr[lane + i * 64];

  // bf16 copy of this token row (contiguous 16 floats per lane; row is
  // L1-resident after the strided read above)
  if (Xb) {
    const float4* xr4 = (const float4*)(xr + lane * 16);
    float4 a0 = xr4[0], a1 = xr4[1], a2 = xr4[2], a3 = xr4[3];
    unsigned short* xbrow = Xb + (size_t)t * D_MODEL + lane * 16;
    *(bf16x8*)(xbrow) = pack8(a0, a1);
    *(bf16x8*)(xbrow + 8) = pack8(a2, a3);
  }

  float logits[NUM_EXPERTS];
#pragma unroll
  for (int e = 0; e < NUM_EXPERTS; ++e) {
    const float* wr = Wg + (size_t)e * D_MODEL;
    float s = 0.f;
#pragma unroll
    for (int i = 0; i < 16; ++i) s += xs[i] * wr[lane + i * 64];
    for (int o = 32; o > 0; o >>= 1) s += __shfl_down(s, o);
    logits[e] = s;  // valid on lane 0
  }

  if (lane == 0) {
    int i0 = 0;
#pragma unroll
    for (int e = 1; e < NUM_EXPERTS; ++e)
      if (logits[e] > logits[i0]) i0 = e;
    int i1 = -1;
#pragma unroll
    for (int e = 0; e < NUM_EXPERTS; ++e) {
      if (e == i0) continue;
      if (i1 < 0 || logits[e] > logits[i1]) i1 = e;
    }
    float w0 = 1.0f / (1.0f + expf(logits[i1] - logits[i0]));
    top_idx[2 * t] = i0; top_idx[2 * t + 1] = i1;
    top_w[2 * t] = w0;   top_w[2 * t + 1] = 1.0f - w0;
  }
}

// ---------------- routing (block 0) + W1/W3 cvt (blocks 1..) ----------------
// On exit: top_idx[k] REWRITTEN to slot index of assignment k.
__global__ __launch_bounds__(256) void route_cvt_kernel(
    int* __restrict__ top_idx,
    const float* __restrict__ top_w,
    int* __restrict__ hdr,
    int* __restrict__ slot_token,
    float* __restrict__ slot_weight,
    const float* __restrict__ W1,
    const float* __restrict__ W3,
    unsigned short* __restrict__ W1b,
    unsigned short* __restrict__ W3b) {
  const int tid = threadIdx.x;  // 256
  if (blockIdx.x != 0) {
    // --- converter role: grid-stride over W1 then W3 ---
    const int wid = blockIdx.x - 1;
    const int stride = (gridDim.x - 1) * 256;
    for (int i = wid * 256 + tid; i < NW8; i += stride) {
      const float4* s = (const float4*)(W1 + (size_t)i * 8);
      float4 a = s[0], b = s[1];
      *(bf16x8*)(W1b + (size_t)i * 8) = pack8(a, b);
    }
    for (int i = wid * 256 + tid; i < NW8; i += stride) {
      const float4* s = (const float4*)(W3 + (size_t)i * 8);
      float4 a = s[0], b = s[1];
      *(bf16x8*)(W3b + (size_t)i * 8) = pack8(a, b);
    }
    return;
  }
  // --- routing role (single block) ---
  __shared__ int cnt[NUM_EXPERTS];
  __shared__ int off[NUM_EXPERTS];
  __shared__ int cur[NUM_EXPERTS];
  if (tid < NUM_EXPERTS) cnt[tid] = 0;
  __syncthreads();
  for (int k = tid; k < NSLOT; k += 256) atomicAdd(&cnt[top_idx[k]], 1);
  __syncthreads();
  if (tid == 0) {
    int o = 0;
    for (int e = 0; e < NUM_EXPERTS; ++e) {
      off[e] = o;
      int p = (cnt[e] + BM - 1) & ~(BM - 1);
      hdr[e] = cnt[e];      // raw count
      hdr[8 + e] = o;       // base slot offset (128-aligned)
      hdr[16 + e] = p;      // padded count
      o += p;
    }
  }
  __syncthreads();
  if (tid < NUM_EXPERTS) cur[tid] = off[tid];
  for (int i = tid; i < SLOT_CAP; i += 256) { slot_token[i] = 0; slot_weight[i] = 0.0f; }
  __syncthreads();
  for (int k = tid; k < NSLOT; k += 256) {
    int e = top_idx[k];
    int p = atomicAdd(&cur[e], 1);
    slot_token[p] = k >> 1;
    slot_weight[p] = top_w[k];
    top_idx[k] = p;  // inverse map: (token,kk) -> slot
  }
}

// ========== GEMM1: single-barrier 2-phase dbuf global_load_lds ==========
// H = silu(Xb W1b^T) * (Xb W3b^T), bf16 in/out. Linear LDS [128][32]/tile.
// blockIdx.z == NUM_EXPERTS (big tier only): W2 fp32->bf16 converter role.
__global__ __launch_bounds__(256) void gemm1_p(
    const unsigned short* __restrict__ Xb,
    const unsigned short* __restrict__ W1b,
    const unsigned short* __restrict__ W3b,
    const int* __restrict__ hdr,
    const int* __restrict__ slot_token,
    unsigned short* __restrict__ H,
    const float* __restrict__ W2src,
    unsigned short* __restrict__ W2dst) {
  if (blockIdx.z == NUM_EXPERTS) {
    // converter role (big tier): 896 blocks grid-stride over W2
    const int wid = blockIdx.y * gridDim.x + blockIdx.x;
    const int stride = gridDim.x * gridDim.y * 256;
    for (int i = wid * 256 + threadIdx.x; i < NW8; i += stride) {
      const float4* s = (const float4*)(W2src + (size_t)i * 8);
      float4 a = s[0], b = s[1];
      *(bf16x8*)(W2dst + (size_t)i * 8) = pack8(a, b);
    }
    return;
  }
  const int e = blockIdx.z;
  const int pad_cnt = hdr[16 + e];
  const int m0 = blockIdx.y * BM;
  if (m0 >= pad_cnt) return;
  const int base = hdr[8 + e];
  const int n0 = blockIdx.x * BN;

  __shared__ unsigned short As[2][BM * BK];    // 2 x 8KB
  __shared__ unsigned short B1s[2][BN * BK];
  __shared__ unsigned short B3s[2][BN * BK];

  const int tid = threadIdx.x;
  const int lane = tid & 63;
  const int wave = tid >> 6;
  const int wm = (wave >> 1) * 64;
  const int wn = (wave & 1) * 64;
  const int l15 = lane & 15;
  const int quad = lane >> 4;

  const int r0 = tid >> 2;          // 0..63
  const int cc = (tid & 3) * 8;
  const int tokA0 = slot_token[base + m0 + r0];
  const int tokA1 = slot_token[base + m0 + 64 + r0];
  const unsigned short* gA0 = Xb + (size_t)tokA0 * D_MODEL + cc;
  const unsigned short* gA1 = Xb + (size_t)tokA1 * D_MODEL + cc;
  const unsigned short* gB1_0 = W1b + ((size_t)e * D_MLP + n0 + r0) * D_MODEL + cc;
  const unsigned short* gB1_1 = gB1_0 + (size_t)64 * D_MODEL;
  const unsigned short* gB3_0 = W3b + ((size_t)e * D_MLP + n0 + r0) * D_MODEL + cc;
  const unsigned short* gB3_1 = gB3_0 + (size_t)64 * D_MODEL;
  const int wb = wave * 512;  // shorts: wave-uniform LDS base (1KB/wave)

  const f32x4 fzero = {0.f, 0.f, 0.f, 0.f};
  f32x4 acc1[4][4], acc3[4][4];
#pragma unroll
  for (int i = 0; i < 4; ++i)
#pragma unroll
    for (int j = 0; j < 4; ++j) { acc1[i][j] = fzero; acc3[i][j] = fzero; }

#define NT1 (D_MODEL / BK)  // 32
  // prologue: stage tile 0 into buffer 0, drain, barrier
  gload16(gA0, &As[0][wb]);
  gload16(gA1, &As[0][2048 + wb]);
  gload16(gB1_0, &B1s[0][wb]);
  gload16(gB1_1, &B1s[0][2048 + wb]);
  gload16(gB3_0, &B3s[0][wb]);
  gload16(gB3_1, &B3s[0][2048 + wb]);
  asm volatile("s_waitcnt vmcnt(0)" ::: "memory");
  __builtin_amdgcn_s_barrier();
  asm volatile("" ::: "memory");

#pragma unroll
  for (int t = 0; t < NT1; ++t) {
    const int p = t & 1;
    if (t + 1 < NT1) {  // stage next tile into other buffer (issue-early)
      const int q = p ^ 1;
      const int k1 = (t + 1) * BK;
      gload16(gA0 + k1, &As[q][wb]);
      gload16(gA1 + k1, &As[q][2048 + wb]);
      gload16(gB1_0 + k1, &B1s[q][wb]);
      gload16(gB1_1 + k1, &B1s[q][2048 + wb]);
      gload16(gB3_0 + k1, &B3s[q][wb]);
      gload16(gB3_1 + k1, &B3s[q][2048 + wb]);
    }
    bf16x8 af[4], b1f[4], b3f[4];
#pragma unroll
    for (int i = 0; i < 4; ++i)
      af[i] = *(const bf16x8*)(&As[p][(wm + i * 16 + l15) * BK + quad * 8]);
#pragma unroll
    for (int j = 0; j < 4; ++j) {
      b1f[j] = *(const bf16x8*)(&B1s[p][(wn + j * 16 + l15) * BK + quad * 8]);
      b3f[j] = *(const bf16x8*)(&B3s[p][(wn + j * 16 + l15) * BK + quad * 8]);
    }
#pragma unroll
    for (int i = 0; i < 4; ++i)
#pragma unroll
      for (int j = 0; j < 4; ++j) {
        acc1[i][j] = __builtin_amdgcn_mfma_f32_16x16x32_bf16(af[i], b1f[j], acc1[i][j], 0, 0, 0);
        acc3[i][j] = __builtin_amdgcn_mfma_f32_16x16x32_bf16(af[i], b3f[j], acc3[i][j], 0, 0, 0);
      }
    if (t + 1 < NT1) {
      // reads of p retired (lgkm before MFMA); drain my stage of q; one barrier
      asm volatile("s_waitcnt vmcnt(0)" ::: "memory");
      __builtin_amdgcn_s_barrier();
      asm volatile("" ::: "memory");
    }
  }

  // epilogue: silu(h1)*h3 -> bf16 H.  D layout: col=lane&15, row=quad*4+reg
  const size_t hbase = (size_t)(base + m0);
#pragma unroll
  for (int i = 0; i < 4; ++i) {
    const int mrow = wm + i * 16 + quad * 4;
#pragma unroll
    for (int r = 0; r < 4; ++r) {
      unsigned short* hrow = H + (hbase + mrow + r) * D_MLP + n0;
#pragma unroll
      for (int j = 0; j < 4; ++j) {
        float h1 = acc1[i][j][r];
        float h3 = acc3[i][j][r];
        float s = h1 / (1.0f + __expf(-h1));
        hrow[wn + j * 16 + l15] = f32_to_bf16(s * h3);
      }
    }
  }
}

// ========== GEMM2: single-barrier 2-phase dbuf global_load_lds ==========
// Y[slot] = H[slot] W2^T  (raw expert_out, fp32; weights applied in combine)
__global__ __launch_bounds__(256) void gemm2_p(
    const unsigned short* __restrict__ H,
    const unsigned short* __restrict__ W2b,
    const int* __restrict__ hdr,
    float* __restrict__ Y) {
  const int e = blockIdx.z;
  const int pad_cnt = hdr[16 + e];
  const int m0 = blockIdx.y * BM;
  if (m0 >= pad_cnt) return;
  const int base = hdr[8 + e];
  const int n0 = blockIdx.x * BN;

  __shared__ unsigned short As[2][BM * BK];   // 2 x 8KB
  __shared__ unsigned short Bs[2][BN * BK];

  const int tid = threadIdx.x;
  const int lane = tid & 63;
  const int wave = tid >> 6;
  const int wm = (wave >> 1) * 64;
  const int wn = (wave & 1) * 64;
  const int l15 = lane & 15;
  const int quad = lane >> 4;

  const int r0 = tid >> 2;          // 0..63
  const int cc = (tid & 3) * 8;
  const unsigned short* gA0 = H + (size_t)(base + m0 + r0) * D_MLP + cc;
  const unsigned short* gA1 = gA0 + (size_t)64 * D_MLP;
  const unsigned short* gB0 = W2b + ((size_t)e * D_MODEL + n0 + r0) * D_MLP + cc;
  const unsigned short* gB1 = gB0 + (size_t)64 * D_MLP;
  const int wb = wave * 512;  // shorts: wave-uniform LDS base

  const f32x4 fzero = {0.f, 0.f, 0.f, 0.f};
  f32x4 acc[4][4];
#pragma unroll
  for (int i = 0; i < 4; ++i)
#pragma unroll
    for (int j = 0; j < 4; ++j) acc[i][j] = fzero;

#define NT2 (D_MLP / BK)  // 112
  // prologue: stage tile 0, drain, barrier
  gload16(gA0, &As[0][wb]);
  gload16(gA1, &As[0][2048 + wb]);
  gload16(gB0, &Bs[0][wb]);
  gload16(gB1, &Bs[0][2048 + wb]);
  asm volatile("s_waitcnt vmcnt(0)" ::: "memory");
  __builtin_amdgcn_s_barrier();
  asm volatile("" ::: "memory");

#pragma unroll 2
  for (int t = 0; t < NT2; ++t) {
    const int p = t & 1;
    if (t + 1 < NT2) {
      const int q = p ^ 1;
      const int k1 = (t + 1) * BK;
      gload16(gA0 + k1, &As[q][wb]);
      gload16(gA1 + k1, &As[q][2048 + wb]);
      gload16(gB0 + k1, &Bs[q][wb]);
      gload16(gB1 + k1, &Bs[q][2048 + wb]);
    }
    bf16x8 af[4], bf[4];
#pragma unroll
    for (int i = 0; i < 4; ++i)
      af[i] = *(const bf16x8*)(&As[p][(wm + i * 16 + l15) * BK + quad * 8]);
#pragma unroll
    for (int j = 0; j < 4; ++j)
      bf[j] = *(const bf16x8*)(&Bs[p][(wn + j * 16 + l15) * BK + quad * 8]);
#pragma unroll
    for (int i = 0; i < 4; ++i)
#pragma unroll
      for (int j = 0; j < 4; ++j)
        acc[i][j] = __builtin_amdgcn_mfma_f32_16x16x32_bf16(af[i], bf[j], acc[i][j], 0, 0, 0);
    if (t + 1 < NT2) {
      asm volatile("s_waitcnt vmcnt(0)" ::: "memory");
      __builtin_amdgcn_s_barrier();
      asm volatile("" ::: "memory");
    }
  }

  // plain fp32 stores per slot row (padding rows harmless: Y is scratch)
#pragma unroll
  for (int i = 0; i < 4; ++i) {
    const int mrow = wm + i * 16 + quad * 4;
#pragma unroll
    for (int r = 0; r < 4; ++r) {
      float* yrow = Y + (size_t)(base + m0 + mrow + r) * D_MODEL + n0;
#pragma unroll
      for (int j = 0; j < 4; ++j)
        yrow[wn + j * 16 + l15] = acc[i][j][r];
    }
  }
}

// ---------------- combine: out[t] = w0*Y[p0] + w1*Y[p1] ----------------
__global__ __launch_bounds__(256) void combine_kernel(
    const float* __restrict__ Y,
    const int* __restrict__ slot_of,   // top_idx rewritten by route
    const float* __restrict__ top_w,
    float* __restrict__ out) {
  const int t = blockIdx.x;
  const int c = threadIdx.x;  // 256 float4s = 1024 floats
  const int p0 = slot_of[2 * t], p1 = slot_of[2 * t + 1];
  const float w0 = top_w[2 * t], w1 = top_w[2 * t + 1];
  const float4 y0 = ((const float4*)(Y + (size_t)p0 * D_MODEL))[c];
  const float4 y1 = ((const float4*)(Y + (size_t)p1 * D_MODEL))[c];
  float4 o;
  o.x = w0 * y0.x + w1 * y1.x;
  o.y = w0 * y0.y + w1 * y1.y;
  o.z = w0 * y0.z + w1 * y1.z;
  o.w = w0 * y0.w + w1 * y1.w;
  ((float4*)(out + (size_t)t * D_MODEL))[c] = o;
}

// ================= OLD PATH (fallback if ws too small) =================

__global__ __launch_bounds__(256) void gemm1_kernel(const float* __restrict__ x,
                             const float* __restrict__ W1,
                             const float* __restrict__ W3,
                             const int* __restrict__ hdr,
                             const int* __restrict__ slot_token,
                             unsigned short* __restrict__ H) {
  const int e = blockIdx.z;
  const int pad_cnt = hdr[16 + e];
  const int m0 = blockIdx.y * BM;
  if (m0 >= pad_cnt) return;
  const int base = hdr[8 + e];
  const int n0 = blockIdx.x * BN;

  __shared__ unsigned short As[BM * LDT];
  __shared__ unsigned short B1s[BN * LDT];
  __shared__ unsigned short B3s[BN * LDT];

  const int tid = threadIdx.x;
  const int lane = tid & 63;
  const int wave = tid >> 6;
  const int wm = (wave >> 1) * 64;
  const int wn = (wave & 1) * 64;
  const int l15 = lane & 15;
  const int quad = lane >> 4;

  const int sr = tid >> 1;
  const int sc = (tid & 1) * 16;
  const float* arow = x + (size_t)slot_token[base + m0 + sr] * D_MODEL + sc;
  const float* b1row = W1 + ((size_t)e * D_MLP + n0 + sr) * D_MODEL + sc;
  const float* b3row = W3 + ((size_t)e * D_MLP + n0 + sr) * D_MODEL + sc;

  const f32x4 fzero = {0.f, 0.f, 0.f, 0.f};
  f32x4 acc1[4][4], acc3[4][4];
#pragma unroll
  for (int i = 0; i < 4; ++i)
#pragma unroll
    for (int j = 0; j < 4; ++j) { acc1[i][j] = fzero; acc3[i][j] = fzero; }

  for (int k0 = 0; k0 < D_MODEL; k0 += BK) {
    const float4* ap = (const float4*)(arow + k0);
    const float4* b1p = (const float4*)(b1row + k0);
    const float4* b3p = (const float4*)(b3row + k0);
    float4 a0 = ap[0], a1 = ap[1], a2 = ap[2], a3 = ap[3];
    float4 c0 = b1p[0], c1 = b1p[1], c2 = b1p[2], c3 = b1p[3];
    float4 d0 = b3p[0], d1 = b3p[1], d2 = b3p[2], d3 = b3p[3];
    __syncthreads();
    *(bf16x8*)(&As[sr * LDT + sc]) = pack8(a0, a1);
    *(bf16x8*)(&As[sr * LDT + sc + 8]) = pack8(a2, a3);
    *(bf16x8*)(&B1s[sr * LDT + sc]) = pack8(c0, c1);
    *(bf16x8*)(&B1s[sr * LDT + sc + 8]) = pack8(c2, c3);
    *(bf16x8*)(&B3s[sr * LDT + sc]) = pack8(d0, d1);
    *(bf16x8*)(&B3s[sr * LDT + sc + 8]) = pack8(d2, d3);
    __syncthreads();

    bf16x8 a_frag[4], b1_frag[4], b3_frag[4];
#pragma unroll
    for (int i = 0; i < 4; ++i)
      a_frag[i] = *(const bf16x8*)(&As[(wm + i * 16 + l15) * LDT + quad * 8]);
#pragma unroll
    for (int j = 0; j < 4; ++j) {
      b1_frag[j] = *(const bf16x8*)(&B1s[(wn + j * 16 + l15) * LDT + quad * 8]);
      b3_frag[j] = *(const bf16x8*)(&B3s[(wn + j * 16 + l15) * LDT + quad * 8]);
    }
#pragma unroll
    for (int i = 0; i < 4; ++i)
#pragma unroll
      for (int j = 0; j < 4; ++j) {
        acc1[i][j] = __builtin_amdgcn_mfma_f32_16x16x32_bf16(a_frag[i], b1_frag[j], acc1[i][j], 0, 0, 0);
        acc3[i][j] = __builtin_amdgcn_mfma_f32_16x16x32_bf16(a_frag[i], b3_frag[j], acc3[i][j], 0, 0, 0);
      }
  }

  const size_t hbase = (size_t)(base + m0);
#pragma unroll
  for (int i = 0; i < 4; ++i) {
    const int mrow = wm + i * 16 + quad * 4;
#pragma unroll
    for (int r = 0; r < 4; ++r) {
      unsigned short* hrow = H + (hbase + mrow + r) * D_MLP + n0;
#pragma unroll
      for (int j = 0; j < 4; ++j) {
        float h1 = acc1[i][j][r];
        float h3 = acc3[i][j][r];
        float s = h1 / (1.0f + __expf(-h1));
        hrow[wn + j * 16 + l15] = f32_to_bf16(s * h3);
      }
    }
  }
}

__global__ __launch_bounds__(256) void gemm2_kernel(const unsigned short* __restrict__ H,
                             const float* __restrict__ W2,
                             const int* __restrict__ hdr,
                             const int* __restrict__ slot_token,
                             const float* __restrict__ slot_weight,
                             float* __restrict__ out) {
  const int e = blockIdx.z;
  const int pad_cnt = hdr[16 + e];
  const int m0 = blockIdx.y * BM;
  if (m0 >= pad_cnt) return;
  const int base = hdr[8 + e];
  const int n0 = blockIdx.x * BN;

  __shared__ unsigned short As[BM * LDT];
  __shared__ unsigned short Bs[BN * LDT];

  const int tid = threadIdx.x;
  const int lane = tid & 63;
  const int wave = tid >> 6;
  const int wm = (wave >> 1) * 64;
  const int wn = (wave & 1) * 64;
  const int l15 = lane & 15;
  const int quad = lane >> 4;

  const int sr = tid >> 1;
  const int sc = (tid & 1) * 16;
  const unsigned short* arow = H + (size_t)(base + m0 + sr) * D_MLP + sc;
  const float* brow = W2 + ((size_t)e * D_MODEL + n0 + sr) * D_MLP + sc;

  const f32x4 fzero = {0.f, 0.f, 0.f, 0.f};
  f32x4 acc[4][4];
#pragma unroll
  for (int i = 0; i < 4; ++i)
#pragma unroll
    for (int j = 0; j < 4; ++j) acc[i][j] = fzero;

  for (int k0 = 0; k0 < D_MLP; k0 += BK) {
    const uint4* ap = (const uint4*)(arow + k0);
    uint4 a0 = ap[0], a1 = ap[1];
    const float4* bp = (const float4*)(brow + k0);
    float4 c0 = bp[0], c1 = bp[1], c2 = bp[2], c3 = bp[3];
    __syncthreads();
    *(uint4*)(&As[sr * LDT + sc]) = a0;
    *(uint4*)(&As[sr * LDT + sc + 8]) = a1;
    *(bf16x8*)(&Bs[sr * LDT + sc]) = pack8(c0, c1);
    *(bf16x8*)(&Bs[sr * LDT + sc + 8]) = pack8(c2, c3);
    __syncthreads();

    bf16x8 a_frag[4], b_frag[4];
#pragma unroll
    for (int i = 0; i < 4; ++i)
      a_frag[i] = *(const bf16x8*)(&As[(wm + i * 16 + l15) * LDT + quad * 8]);
#pragma unroll
    for (int j = 0; j < 4; ++j)
      b_frag[j] = *(const bf16x8*)(&Bs[(wn + j * 16 + l15) * LDT + quad * 8]);
#pragma unroll
    for (int i = 0; i < 4; ++i)
#pragma unroll
      for (int j = 0; j < 4; ++j)
        acc[i][j] = __builtin_amdgcn_mfma_f32_16x16x32_bf16(a_frag[i], b_frag[j], acc[i][j], 0, 0, 0);
  }

#pragma unroll
  for (int i = 0; i < 4; ++i) {
    const int mrow = wm + i * 16 + quad * 4;
#pragma unroll
    for (int r = 0; r < 4; ++r) {
      const int srow = base + m0 + mrow + r;
      const float w = slot_weight[srow];
      if (w != 0.0f) {
        const int tok = slot_token[srow];
        float* orow = out + (size_t)tok * D_MODEL + n0;
#pragma unroll
        for (int j = 0; j < 4; ++j)
          atomicAdd(&orow[wn + j * 16 + l15], acc[i][j][r] * w);
      }
    }
  }
}

extern "C" void kernel_launch(void* const* d_in, const int* in_sizes, int n_in,
                              void* d_out, int out_size, void* d_ws, size_t ws_size,
                              hipStream_t stream) {
  const float* x  = (const float*)d_in[0];
  const float* Wg = (const float*)d_in[1];
  const float* W1 = (const float*)d_in[2];
  const float* W3 = (const float*)d_in[3];
  const float* W2 = (const float*)d_in[4];
  float* out = (float*)d_out;

  if (ws_size < WS_NEEDED_OLD) return;  // clean failure, no OOB

  char* ws = (char*)d_ws;
  int*   top_idx     = (int*)(ws);                 // 8192 ints (-> slot map after route)
  float* top_w       = (float*)(ws + 32768);       // 8192 floats
  int*   hdr         = (int*)(ws + 65536);         // 64 ints
  int*   slot_token  = (int*)(ws + 65792);         // 9216 ints
  float* slot_weight = (float*)(ws + 102656);      // 9216 floats
  unsigned short* H  = (unsigned short*)(ws + WS_SMALL);

  if (ws_size >= WS_FULL) {
    unsigned short* Xb  = (unsigned short*)(ws + XB_OFF);
    unsigned short* W1b = (unsigned short*)(ws + W1B_OFF);
    unsigned short* W3b = (unsigned short*)(ws + W3B_OFF);
    float* Y = (float*)(ws + W3B_OFF);          // overlay W3b after gemm1
    const bool big = (ws_size >= WS_BIG);
    unsigned short* W2b = big ? (unsigned short*)(ws + W2B_OFF)
                              : W1b;            // mid tier: overlay after gemm1

    gate_kernel<<<T_TOKENS, 64, 0, stream>>>(x, Wg, top_idx, top_w, Xb);
    route_cvt_kernel<<<2049, 256, 0, stream>>>(top_idx, top_w, hdr, slot_token,
                                               slot_weight, W1, W3, W1b, W3b);
    if (big) {
      // z==8 slice converts W2 overlapped with the GEMM blocks
      gemm1_p<<<dim3(D_MLP / BN, T_TOKENS / BM, NUM_EXPERTS + 1), 256, 0, stream>>>(
          Xb, W1b, W3b, hdr, slot_token, H, W2, W2b);
    } else {
      gemm1_p<<<dim3(D_MLP / BN, T_TOKENS / BM, NUM_EXPERTS), 256, 0, stream>>>(
          Xb, W1b, W3b, hdr, slot_token, H, nullptr, nullptr);
      cvt_kernel<<<2048, 256, 0, stream>>>(W2, W2b, NW8);
    }
    gemm2_p<<<dim3(D_MODEL / BN, T_TOKENS / BM, NUM_EXPERTS), 256, 0, stream>>>(
        H, W2b, hdr, Y);
    combine_kernel<<<T_TOKENS, 256, 0, stream>>>(Y, top_idx, top_w, out);
  } else {
    gate_kernel<<<T_TOKENS, 64, 0, stream>>>(x, Wg, top_idx, top_w, nullptr);
    route_cvt_kernel<<<1, 256, 0, stream>>>(top_idx, top_w, hdr, slot_token,
                                            slot_weight, nullptr, nullptr,
                                            nullptr, nullptr);
    zero_kernel<<<(out_size / 4 + 255) / 256, 256, 0, stream>>>((float4*)d_out, out_size / 4);
    gemm1_kernel<<<dim3(D_MLP / BN, T_TOKENS / BM, NUM_EXPERTS), 256, 0, stream>>>(
        x, W1, W3, hdr, slot_token, H);
    gemm2_kernel<<<dim3(D_MODEL / BN, T_TOKENS / BM, NUM_EXPERTS), 256, 0, stream>>>(
        H, W2, hdr, slot_token, slot_weight, out);
  }
}

// Round 7
// 630.882 us; speedup vs baseline: 1.1283x; 1.1283x over previous
//
#include <hip/hip_runtime.h>
#include <hip/hip_bf16.h>
#include <math.h>

// MoE top-2/8, T=4096, d=1024, ffn=3584. fp32 in/out, bf16 MFMA internally.
// R10: revert to R8's proven GEMM loops (two-barrier counted vmcnt: gemm1
// measured 153us; R9's single-barrier shrank the prefetch window and its
// in-grid W2 converter stole BW from gemm1 -> 252us). Keep gate-writes-Xb.
// Consolidate ALL weight conversion (W1+W3+W2, 530MB) into route_cvt's
// converter blocks (big tier, ws>=250MB proven granted by R9's WRITE_SIZE):
// 5 dispatches total, no BW-heavy work fused into GEMM grids.

#define NUM_EXPERTS 8
#define TOPK 2
#define D_MODEL 1024
#define D_MLP 3584
#define T_TOKENS 4096
#define NSLOT (T_TOKENS * TOPK)
#define SLOT_CAP 9216  // 8192 + 8*128 worst-case padding

#define BM 128
#define BN 128
#define BK 32
#define LDT 40  // LDS row pitch for fallback reg-staged kernels (32 + 8 pad)

typedef __attribute__((ext_vector_type(8))) short bf16x8;
typedef __attribute__((ext_vector_type(4))) float f32x4;

// ---- workspace layout ----
// [0, 147456)                small buffers (top_idx/top_w/hdr/slots)
// [147456, +66,060,288)      H bf16 [SLOT_CAP][D_MLP]
// Xb  bf16 [T][D_MODEL]      8,388,608 B
// W1b bf16 [E][D_MLP][D]    58,720,256 B
// W3b bf16 [E][D_MLP][D]    58,720,256 B  (Y fp32 37.7MB overlays after gemm1)
// W2b (big tier only)       58,720,256 B  (mid tier: W2b overlays W1b)
#define WS_SMALL 147456
#define H_BYTES ((size_t)SLOT_CAP * D_MLP * 2)
#define XB_OFF (WS_SMALL + H_BYTES)
#define XB_BYTES ((size_t)T_TOKENS * D_MODEL * 2)
#define W1B_OFF (XB_OFF + XB_BYTES)
#define W13_BYTES ((size_t)NUM_EXPERTS * (size_t)D_MLP * D_MODEL * 2)
#define W3B_OFF (W1B_OFF + W13_BYTES)
#define WS_FULL (W3B_OFF + W13_BYTES)          // 192,036,864
#define W2B_OFF WS_FULL
#define WS_BIG (W2B_OFF + W13_BYTES)           // 250,757,120 (granted: R9 ran big tier)
#define WS_NEEDED_OLD (WS_SMALL + H_BYTES)     // 66,207,744

#define NW8 (NUM_EXPERTS * D_MLP * D_MODEL / 8)  // 3,670,016 chunks of 8

__device__ inline unsigned short f32_to_bf16(float f) {
  union { float f; unsigned int u; } v; v.f = f;
  unsigned int u = v.u;
  unsigned int r = (u + 0x7FFFu + ((u >> 16) & 1u)) >> 16;  // RNE
  return (unsigned short)r;
}

__device__ inline bf16x8 pack8(float4 a, float4 b) {
  bf16x8 v;
  v[0] = (short)f32_to_bf16(a.x); v[1] = (short)f32_to_bf16(a.y);
  v[2] = (short)f32_to_bf16(a.z); v[3] = (short)f32_to_bf16(a.w);
  v[4] = (short)f32_to_bf16(b.x); v[5] = (short)f32_to_bf16(b.y);
  v[6] = (short)f32_to_bf16(b.z); v[7] = (short)f32_to_bf16(b.w);
  return v;
}

__device__ __forceinline__ void gload16(const void* g, void* l) {
  __builtin_amdgcn_global_load_lds(
      (__attribute__((address_space(1))) void*)g,
      (__attribute__((address_space(3))) void*)l, 16, 0, 0);
}

// ---------------- zero d_out (fallback path only) ----------------
__global__ void zero_kernel(float4* __restrict__ p, int n4) {
  int i = blockIdx.x * blockDim.x + threadIdx.x;
  if (i < n4) p[i] = make_float4(0.f, 0.f, 0.f, 0.f);
}

// ---------------- fp32 -> bf16 streaming convert (mid-tier W2) -------------
__global__ __launch_bounds__(256) void cvt_kernel(const float* __restrict__ src,
                                                  unsigned short* __restrict__ dst,
                                                  int n8) {
  int i = blockIdx.x * blockDim.x + threadIdx.x;
  const int stride = gridDim.x * blockDim.x;
  for (; i < n8; i += stride) {
    const float4* s = (const float4*)(src + (size_t)i * 8);
    float4 a = s[0], b = s[1];
    *(bf16x8*)(dst + (size_t)i * 8) = pack8(a, b);
  }
}

// ---------------- gating: one wave per token; also writes Xb ----------------
__global__ __launch_bounds__(64) void gate_kernel(const float* __restrict__ x,
                            const float* __restrict__ Wg,
                            int* __restrict__ top_idx,
                            float* __restrict__ top_w,
                            unsigned short* __restrict__ Xb) {
  const int t = blockIdx.x;
  const int lane = threadIdx.x;  // 64 threads
  const float* xr = x + (size_t)t * D_MODEL;

  float xs[16];
#pragma unroll
  for (int i = 0; i < 16; ++i) xs[i] = xr[lane + i * 64];

  // bf16 copy of this token row (row is L1/L2-resident after read above)
  if (Xb) {
    const float4* xr4 = (const float4*)(xr + lane * 16);
    float4 a0 = xr4[0], a1 = xr4[1], a2 = xr4[2], a3 = xr4[3];
    unsigned short* xbrow = Xb + (size_t)t * D_MODEL + lane * 16;
    *(bf16x8*)(xbrow) = pack8(a0, a1);
    *(bf16x8*)(xbrow + 8) = pack8(a2, a3);
  }

  float logits[NUM_EXPERTS];
#pragma unroll
  for (int e = 0; e < NUM_EXPERTS; ++e) {
    const float* wr = Wg + (size_t)e * D_MODEL;
    float s = 0.f;
#pragma unroll
    for (int i = 0; i < 16; ++i) s += xs[i] * wr[lane + i * 64];
    for (int o = 32; o > 0; o >>= 1) s += __shfl_down(s, o);
    logits[e] = s;  // valid on lane 0
  }

  if (lane == 0) {
    int i0 = 0;
#pragma unroll
    for (int e = 1; e < NUM_EXPERTS; ++e)
      if (logits[e] > logits[i0]) i0 = e;
    int i1 = -1;
#pragma unroll
    for (int e = 0; e < NUM_EXPERTS; ++e) {
      if (e == i0) continue;
      if (i1 < 0 || logits[e] > logits[i1]) i1 = e;
    }
    float w0 = 1.0f / (1.0f + expf(logits[i1] - logits[i0]));
    top_idx[2 * t] = i0; top_idx[2 * t + 1] = i1;
    top_w[2 * t] = w0;   top_w[2 * t + 1] = 1.0f - w0;
  }
}

// ------- routing (block 0) + W1/W3[/W2] cvt (blocks 1..) -------
// On exit: top_idx[k] REWRITTEN to slot index of assignment k.
__global__ __launch_bounds__(256) void route_cvt_kernel(
    int* __restrict__ top_idx,
    const float* __restrict__ top_w,
    int* __restrict__ hdr,
    int* __restrict__ slot_token,
    float* __restrict__ slot_weight,
    const float* __restrict__ W1,
    const float* __restrict__ W3,
    const float* __restrict__ W2,      // nullptr on mid tier
    unsigned short* __restrict__ W1b,
    unsigned short* __restrict__ W3b,
    unsigned short* __restrict__ W2b) {
  const int tid = threadIdx.x;  // 256
  if (blockIdx.x != 0) {
    // --- converter role: grid-stride over W1, W3 (and W2 on big tier) ---
    const int wid = blockIdx.x - 1;
    const int stride = (gridDim.x - 1) * 256;
    for (int i = wid * 256 + tid; i < NW8; i += stride) {
      const float4* s = (const float4*)(W1 + (size_t)i * 8);
      float4 a = s[0], b = s[1];
      *(bf16x8*)(W1b + (size_t)i * 8) = pack8(a, b);
    }
    for (int i = wid * 256 + tid; i < NW8; i += stride) {
      const float4* s = (const float4*)(W3 + (size_t)i * 8);
      float4 a = s[0], b = s[1];
      *(bf16x8*)(W3b + (size_t)i * 8) = pack8(a, b);
    }
    if (W2) {
      for (int i = wid * 256 + tid; i < NW8; i += stride) {
        const float4* s = (const float4*)(W2 + (size_t)i * 8);
        float4 a = s[0], b = s[1];
        *(bf16x8*)(W2b + (size_t)i * 8) = pack8(a, b);
      }
    }
    return;
  }
  // --- routing role (single block) ---
  __shared__ int cnt[NUM_EXPERTS];
  __shared__ int off[NUM_EXPERTS];
  __shared__ int cur[NUM_EXPERTS];
  if (tid < NUM_EXPERTS) cnt[tid] = 0;
  __syncthreads();
  for (int k = tid; k < NSLOT; k += 256) atomicAdd(&cnt[top_idx[k]], 1);
  __syncthreads();
  if (tid == 0) {
    int o = 0;
    for (int e = 0; e < NUM_EXPERTS; ++e) {
      off[e] = o;
      int p = (cnt[e] + BM - 1) & ~(BM - 1);
      hdr[e] = cnt[e];      // raw count
      hdr[8 + e] = o;       // base slot offset (128-aligned)
      hdr[16 + e] = p;      // padded count
      o += p;
    }
  }
  __syncthreads();
  if (tid < NUM_EXPERTS) cur[tid] = off[tid];
  for (int i = tid; i < SLOT_CAP; i += 256) { slot_token[i] = 0; slot_weight[i] = 0.0f; }
  __syncthreads();
  for (int k = tid; k < NSLOT; k += 256) {
    int e = top_idx[k];
    int p = atomicAdd(&cur[e], 1);
    slot_token[p] = k >> 1;
    slot_weight[p] = top_w[k];
    top_idx[k] = p;  // inverse map: (token,kk) -> slot
  }
}

// ========== GEMM1: 2-phase dbuf global_load_lds + counted vmcnt (R8) ==========
// H = silu(Xb W1b^T) * (Xb W3b^T), bf16 in/out. Linear LDS [128][32] per tile.
__global__ __launch_bounds__(256) void gemm1_p(
    const unsigned short* __restrict__ Xb,
    const unsigned short* __restrict__ W1b,
    const unsigned short* __restrict__ W3b,
    const int* __restrict__ hdr,
    const int* __restrict__ slot_token,
    unsigned short* __restrict__ H) {
  const int e = blockIdx.z;
  const int pad_cnt = hdr[16 + e];
  const int m0 = blockIdx.y * BM;
  if (m0 >= pad_cnt) return;
  const int base = hdr[8 + e];
  const int n0 = blockIdx.x * BN;

  __shared__ unsigned short As[2][BM * BK];    // 2 x 8KB
  __shared__ unsigned short B1s[2][BN * BK];
  __shared__ unsigned short B3s[2][BN * BK];

  const int tid = threadIdx.x;
  const int lane = tid & 63;
  const int wave = tid >> 6;
  const int wm = (wave >> 1) * 64;
  const int wn = (wave & 1) * 64;
  const int l15 = lane & 15;
  const int quad = lane >> 4;

  const int r0 = tid >> 2;          // 0..63
  const int cc = (tid & 3) * 8;
  const int tokA0 = slot_token[base + m0 + r0];
  const int tokA1 = slot_token[base + m0 + 64 + r0];
  const unsigned short* gA0 = Xb + (size_t)tokA0 * D_MODEL + cc;
  const unsigned short* gA1 = Xb + (size_t)tokA1 * D_MODEL + cc;
  const unsigned short* gB1_0 = W1b + ((size_t)e * D_MLP + n0 + r0) * D_MODEL + cc;
  const unsigned short* gB1_1 = gB1_0 + (size_t)64 * D_MODEL;
  const unsigned short* gB3_0 = W3b + ((size_t)e * D_MLP + n0 + r0) * D_MODEL + cc;
  const unsigned short* gB3_1 = gB3_0 + (size_t)64 * D_MODEL;
  const int wb = wave * 512;  // shorts: wave-uniform LDS base (1KB/wave)

  const f32x4 fzero = {0.f, 0.f, 0.f, 0.f};
  f32x4 acc1[4][4], acc3[4][4];
#pragma unroll
  for (int i = 0; i < 4; ++i)
#pragma unroll
    for (int j = 0; j < 4; ++j) { acc1[i][j] = fzero; acc3[i][j] = fzero; }

#define NT1 (D_MODEL / BK)  // 32
  // prologue: stage tile 0 into buffer 0 (6 loads in flight)
  gload16(gA0, &As[0][wb]);
  gload16(gA1, &As[0][2048 + wb]);
  gload16(gB1_0, &B1s[0][wb]);
  gload16(gB1_1, &B1s[0][2048 + wb]);
  gload16(gB3_0, &B3s[0][wb]);
  gload16(gB3_1, &B3s[0][2048 + wb]);

#pragma unroll
  for (int t = 0; t < NT1; ++t) {
    const int p = t & 1;
    if (t + 1 < NT1) {
      const int q = (t + 1) & 1;
      const int k1 = (t + 1) * BK;
      gload16(gA0 + k1, &As[q][wb]);
      gload16(gA1 + k1, &As[q][2048 + wb]);
      gload16(gB1_0 + k1, &B1s[q][wb]);
      gload16(gB1_1 + k1, &B1s[q][2048 + wb]);
      gload16(gB3_0 + k1, &B3s[q][wb]);
      gload16(gB3_1 + k1, &B3s[q][2048 + wb]);
      // wait for tile p's 6 loads (oldest); leave tile q's 6 in flight
      asm volatile("s_waitcnt vmcnt(6)" ::: "memory");
    } else {
      asm volatile("s_waitcnt vmcnt(0)" ::: "memory");
    }
    __builtin_amdgcn_s_barrier();   // all waves' p-loads landed
    asm volatile("" ::: "memory");

    bf16x8 af[4], b1f[4], b3f[4];
#pragma unroll
    for (int i = 0; i < 4; ++i)
      af[i] = *(const bf16x8*)(&As[p][(wm + i * 16 + l15) * BK + quad * 8]);
#pragma unroll
    for (int j = 0; j < 4; ++j) {
      b1f[j] = *(const bf16x8*)(&B1s[p][(wn + j * 16 + l15) * BK + quad * 8]);
      b3f[j] = *(const bf16x8*)(&B3s[p][(wn + j * 16 + l15) * BK + quad * 8]);
    }
#pragma unroll
    for (int i = 0; i < 4; ++i)
#pragma unroll
      for (int j = 0; j < 4; ++j) {
        acc1[i][j] = __builtin_amdgcn_mfma_f32_16x16x32_bf16(af[i], b1f[j], acc1[i][j], 0, 0, 0);
        acc3[i][j] = __builtin_amdgcn_mfma_f32_16x16x32_bf16(af[i], b3f[j], acc3[i][j], 0, 0, 0);
      }
    asm volatile("" ::: "memory");
    __builtin_amdgcn_s_barrier();   // reads of p done; next iter may overwrite p
  }

  // epilogue: silu(h1)*h3 -> bf16 H.  D layout: col=lane&15, row=quad*4+reg
  const size_t hbase = (size_t)(base + m0);
#pragma unroll
  for (int i = 0; i < 4; ++i) {
    const int mrow = wm + i * 16 + quad * 4;
#pragma unroll
    for (int r = 0; r < 4; ++r) {
      unsigned short* hrow = H + (hbase + mrow + r) * D_MLP + n0;
#pragma unroll
      for (int j = 0; j < 4; ++j) {
        float h1 = acc1[i][j][r];
        float h3 = acc3[i][j][r];
        float s = h1 / (1.0f + __expf(-h1));
        hrow[wn + j * 16 + l15] = f32_to_bf16(s * h3);
      }
    }
  }
}

// ========== GEMM2: 2-phase dbuf global_load_lds + counted vmcnt (R8) ==========
// Y[slot] = H[slot] W2^T  (raw expert_out, fp32; weights applied in combine)
__global__ __launch_bounds__(256) void gemm2_p(
    const unsigned short* __restrict__ H,
    const unsigned short* __restrict__ W2b,
    const int* __restrict__ hdr,
    float* __restrict__ Y) {
  const int e = blockIdx.z;
  const int pad_cnt = hdr[16 + e];
  const int m0 = blockIdx.y * BM;
  if (m0 >= pad_cnt) return;
  const int base = hdr[8 + e];
  const int n0 = blockIdx.x * BN;

  __shared__ unsigned short As[2][BM * BK];   // 2 x 8KB
  __shared__ unsigned short Bs[2][BN * BK];

  const int tid = threadIdx.x;
  const int lane = tid & 63;
  const int wave = tid >> 6;
  const int wm = (wave >> 1) * 64;
  const int wn = (wave & 1) * 64;
  const int l15 = lane & 15;
  const int quad = lane >> 4;

  const int r0 = tid >> 2;          // 0..63
  const int cc = (tid & 3) * 8;
  const unsigned short* gA0 = H + (size_t)(base + m0 + r0) * D_MLP + cc;
  const unsigned short* gA1 = gA0 + (size_t)64 * D_MLP;
  const unsigned short* gB0 = W2b + ((size_t)e * D_MODEL + n0 + r0) * D_MLP + cc;
  const unsigned short* gB1 = gB0 + (size_t)64 * D_MLP;
  const int wb = wave * 512;  // shorts: wave-uniform LDS base

  const f32x4 fzero = {0.f, 0.f, 0.f, 0.f};
  f32x4 acc[4][4];
#pragma unroll
  for (int i = 0; i < 4; ++i)
#pragma unroll
    for (int j = 0; j < 4; ++j) acc[i][j] = fzero;

#define NT2 (D_MLP / BK)  // 112
  // prologue: stage tile 0 into buffer 0 (4 loads in flight)
  gload16(gA0, &As[0][wb]);
  gload16(gA1, &As[0][2048 + wb]);
  gload16(gB0, &Bs[0][wb]);
  gload16(gB1, &Bs[0][2048 + wb]);

#pragma unroll 2
  for (int t = 0; t < NT2; ++t) {
    const int p = t & 1;
    if (t + 1 < NT2) {
      const int q = (t + 1) & 1;
      const int k1 = (t + 1) * BK;
      gload16(gA0 + k1, &As[q][wb]);
      gload16(gA1 + k1, &As[q][2048 + wb]);
      gload16(gB0 + k1, &Bs[q][wb]);
      gload16(gB1 + k1, &Bs[q][2048 + wb]);
      asm volatile("s_waitcnt vmcnt(4)" ::: "memory");
    } else {
      asm volatile("s_waitcnt vmcnt(0)" ::: "memory");
    }
    __builtin_amdgcn_s_barrier();   // all waves' p-loads landed
    asm volatile("" ::: "memory");

    bf16x8 af[4], bf[4];
#pragma unroll
    for (int i = 0; i < 4; ++i)
      af[i] = *(const bf16x8*)(&As[p][(wm + i * 16 + l15) * BK + quad * 8]);
#pragma unroll
    for (int j = 0; j < 4; ++j)
      bf[j] = *(const bf16x8*)(&Bs[p][(wn + j * 16 + l15) * BK + quad * 8]);
#pragma unroll
    for (int i = 0; i < 4; ++i)
#pragma unroll
      for (int j = 0; j < 4; ++j)
        acc[i][j] = __builtin_amdgcn_mfma_f32_16x16x32_bf16(af[i], bf[j], acc[i][j], 0, 0, 0);
    asm volatile("" ::: "memory");
    __builtin_amdgcn_s_barrier();   // reads of p done; next iter may overwrite p
  }

  // plain fp32 stores per slot row (padding rows harmless: Y is scratch)
#pragma unroll
  for (int i = 0; i < 4; ++i) {
    const int mrow = wm + i * 16 + quad * 4;
#pragma unroll
    for (int r = 0; r < 4; ++r) {
      float* yrow = Y + (size_t)(base + m0 + mrow + r) * D_MODEL + n0;
#pragma unroll
      for (int j = 0; j < 4; ++j)
        yrow[wn + j * 16 + l15] = acc[i][j][r];
    }
  }
}

// ---------------- combine: out[t] = w0*Y[p0] + w1*Y[p1] ----------------
__global__ __launch_bounds__(256) void combine_kernel(
    const float* __restrict__ Y,
    const int* __restrict__ slot_of,   // top_idx rewritten by route
    const float* __restrict__ top_w,
    float* __restrict__ out) {
  const int t = blockIdx.x;
  const int c = threadIdx.x;  // 256 float4s = 1024 floats
  const int p0 = slot_of[2 * t], p1 = slot_of[2 * t + 1];
  const float w0 = top_w[2 * t], w1 = top_w[2 * t + 1];
  const float4 y0 = ((const float4*)(Y + (size_t)p0 * D_MODEL))[c];
  const float4 y1 = ((const float4*)(Y + (size_t)p1 * D_MODEL))[c];
  float4 o;
  o.x = w0 * y0.x + w1 * y1.x;
  o.y = w0 * y0.y + w1 * y1.y;
  o.z = w0 * y0.z + w1 * y1.z;
  o.w = w0 * y0.w + w1 * y1.w;
  ((float4*)(out + (size_t)t * D_MODEL))[c] = o;
}

// ================= OLD PATH (fallback if ws too small) =================

__global__ __launch_bounds__(256) void gemm1_kernel(const float* __restrict__ x,
                             const float* __restrict__ W1,
                             const float* __restrict__ W3,
                             const int* __restrict__ hdr,
                             const int* __restrict__ slot_token,
                             unsigned short* __restrict__ H) {
  const int e = blockIdx.z;
  const int pad_cnt = hdr[16 + e];
  const int m0 = blockIdx.y * BM;
  if (m0 >= pad_cnt) return;
  const int base = hdr[8 + e];
  const int n0 = blockIdx.x * BN;

  __shared__ unsigned short As[BM * LDT];
  __shared__ unsigned short B1s[BN * LDT];
  __shared__ unsigned short B3s[BN * LDT];

  const int tid = threadIdx.x;
  const int lane = tid & 63;
  const int wave = tid >> 6;
  const int wm = (wave >> 1) * 64;
  const int wn = (wave & 1) * 64;
  const int l15 = lane & 15;
  const int quad = lane >> 4;

  const int sr = tid >> 1;
  const int sc = (tid & 1) * 16;
  const float* arow = x + (size_t)slot_token[base + m0 + sr] * D_MODEL + sc;
  const float* b1row = W1 + ((size_t)e * D_MLP + n0 + sr) * D_MODEL + sc;
  const float* b3row = W3 + ((size_t)e * D_MLP + n0 + sr) * D_MODEL + sc;

  const f32x4 fzero = {0.f, 0.f, 0.f, 0.f};
  f32x4 acc1[4][4], acc3[4][4];
#pragma unroll
  for (int i = 0; i < 4; ++i)
#pragma unroll
    for (int j = 0; j < 4; ++j) { acc1[i][j] = fzero; acc3[i][j] = fzero; }

  for (int k0 = 0; k0 < D_MODEL; k0 += BK) {
    const float4* ap = (const float4*)(arow + k0);
    const float4* b1p = (const float4*)(b1row + k0);
    const float4* b3p = (const float4*)(b3row + k0);
    float4 a0 = ap[0], a1 = ap[1], a2 = ap[2], a3 = ap[3];
    float4 c0 = b1p[0], c1 = b1p[1], c2 = b1p[2], c3 = b1p[3];
    float4 d0 = b3p[0], d1 = b3p[1], d2 = b3p[2], d3 = b3p[3];
    __syncthreads();
    *(bf16x8*)(&As[sr * LDT + sc]) = pack8(a0, a1);
    *(bf16x8*)(&As[sr * LDT + sc + 8]) = pack8(a2, a3);
    *(bf16x8*)(&B1s[sr * LDT + sc]) = pack8(c0, c1);
    *(bf16x8*)(&B1s[sr * LDT + sc + 8]) = pack8(c2, c3);
    *(bf16x8*)(&B3s[sr * LDT + sc]) = pack8(d0, d1);
    *(bf16x8*)(&B3s[sr * LDT + sc + 8]) = pack8(d2, d3);
    __syncthreads();

    bf16x8 a_frag[4], b1_frag[4], b3_frag[4];
#pragma unroll
    for (int i = 0; i < 4; ++i)
      a_frag[i] = *(const bf16x8*)(&As[(wm + i * 16 + l15) * LDT + quad * 8]);
#pragma unroll
    for (int j = 0; j < 4; ++j) {
      b1_frag[j] = *(const bf16x8*)(&B1s[(wn + j * 16 + l15) * LDT + quad * 8]);
      b3_frag[j] = *(const bf16x8*)(&B3s[(wn + j * 16 + l15) * LDT + quad * 8]);
    }
#pragma unroll
    for (int i = 0; i < 4; ++i)
#pragma unroll
      for (int j = 0; j < 4; ++j) {
        acc1[i][j] = __builtin_amdgcn_mfma_f32_16x16x32_bf16(a_frag[i], b1_frag[j], acc1[i][j], 0, 0, 0);
        acc3[i][j] = __builtin_amdgcn_mfma_f32_16x16x32_bf16(a_frag[i], b3_frag[j], acc3[i][j], 0, 0, 0);
      }
  }

  const size_t hbase = (size_t)(base + m0);
#pragma unroll
  for (int i = 0; i < 4; ++i) {
    const int mrow = wm + i * 16 + quad * 4;
#pragma unroll
    for (int r = 0; r < 4; ++r) {
      unsigned short* hrow = H + (hbase + mrow + r) * D_MLP + n0;
#pragma unroll
      for (int j = 0; j < 4; ++j) {
        float h1 = acc1[i][j][r];
        float h3 = acc3[i][j][r];
        float s = h1 / (1.0f + __expf(-h1));
        hrow[wn + j * 16 + l15] = f32_to_bf16(s * h3);
      }
    }
  }
}

__global__ __launch_bounds__(256) void gemm2_kernel(const unsigned short* __restrict__ H,
                             const float* __restrict__ W2,
                             const int* __restrict__ hdr,
                             const int* __restrict__ slot_token,
                             const float* __restrict__ slot_weight,
                             float* __restrict__ out) {
  const int e = blockIdx.z;
  const int pad_cnt = hdr[16 + e];
  const int m0 = blockIdx.y * BM;
  if (m0 >= pad_cnt) return;
  const int base = hdr[8 + e];
  const int n0 = blockIdx.x * BN;

  __shared__ unsigned short As[BM * LDT];
  __shared__ unsigned short Bs[BN * LDT];

  const int tid = threadIdx.x;
  const int lane = tid & 63;
  const int wave = tid >> 6;
  const int wm = (wave >> 1) * 64;
  const int wn = (wave & 1) * 64;
  const int l15 = lane & 15;
  const int quad = lane >> 4;

  const int sr = tid >> 1;
  const int sc = (tid & 1) * 16;
  const unsigned short* arow = H + (size_t)(base + m0 + sr) * D_MLP + sc;
  const float* brow = W2 + ((size_t)e * D_MODEL + n0 + sr) * D_MLP + sc;

  const f32x4 fzero = {0.f, 0.f, 0.f, 0.f};
  f32x4 acc[4][4];
#pragma unroll
  for (int i = 0; i < 4; ++i)
#pragma unroll
    for (int j = 0; j < 4; ++j) acc[i][j] = fzero;

  for (int k0 = 0; k0 < D_MLP; k0 += BK) {
    const uint4* ap = (const uint4*)(arow + k0);
    uint4 a0 = ap[0], a1 = ap[1];
    const float4* bp = (const float4*)(brow + k0);
    float4 c0 = bp[0], c1 = bp[1], c2 = bp[2], c3 = bp[3];
    __syncthreads();
    *(uint4*)(&As[sr * LDT + sc]) = a0;
    *(uint4*)(&As[sr * LDT + sc + 8]) = a1;
    *(bf16x8*)(&Bs[sr * LDT + sc]) = pack8(c0, c1);
    *(bf16x8*)(&Bs[sr * LDT + sc + 8]) = pack8(c2, c3);
    __syncthreads();

    bf16x8 a_frag[4], b_frag[4];
#pragma unroll
    for (int i = 0; i < 4; ++i)
      a_frag[i] = *(const bf16x8*)(&As[(wm + i * 16 + l15) * LDT + quad * 8]);
#pragma unroll
    for (int j = 0; j < 4; ++j)
      b_frag[j] = *(const bf16x8*)(&Bs[(wn + j * 16 + l15) * LDT + quad * 8]);
#pragma unroll
    for (int i = 0; i < 4; ++i)
#pragma unroll
      for (int j = 0; j < 4; ++j)
        acc[i][j] = __builtin_amdgcn_mfma_f32_16x16x32_bf16(a_frag[i], b_frag[j], acc[i][j], 0, 0, 0);
  }

#pragma unroll
  for (int i = 0; i < 4; ++i) {
    const int mrow = wm + i * 16 + quad * 4;
#pragma unroll
    for (int r = 0; r < 4; ++r) {
      const int srow = base + m0 + mrow + r;
      const float w = slot_weight[srow];
      if (w != 0.0f) {
        const int tok = slot_token[srow];
        float* orow = out + (size_t)tok * D_MODEL + n0;
#pragma unroll
        for (int j = 0; j < 4; ++j)
          atomicAdd(&orow[wn + j * 16 + l15], acc[i][j][r] * w);
      }
    }
  }
}

extern "C" void kernel_launch(void* const* d_in, const int* in_sizes, int n_in,
                              void* d_out, int out_size, void* d_ws, size_t ws_size,
                              hipStream_t stream) {
  const float* x  = (const float*)d_in[0];
  const float* Wg = (const float*)d_in[1];
  const float* W1 = (const float*)d_in[2];
  const float* W3 = (const float*)d_in[3];
  const float* W2 = (const float*)d_in[4];
  float* out = (float*)d_out;

  if (ws_size < WS_NEEDED_OLD) return;  // clean failure, no OOB

  char* ws = (char*)d_ws;
  int*   top_idx     = (int*)(ws);                 // 8192 ints (-> slot map after route)
  float* top_w       = (float*)(ws + 32768);       // 8192 floats
  int*   hdr         = (int*)(ws + 65536);         // 64 ints
  int*   slot_token  = (int*)(ws + 65792);         // 9216 ints
  float* slot_weight = (float*)(ws + 102656);      // 9216 floats
  unsigned short* H  = (unsigned short*)(ws + WS_SMALL);

  if (ws_size >= WS_FULL) {
    unsigned short* Xb  = (unsigned short*)(ws + XB_OFF);
    unsigned short* W1b = (unsigned short*)(ws + W1B_OFF);
    unsigned short* W3b = (unsigned short*)(ws + W3B_OFF);
    float* Y = (float*)(ws + W3B_OFF);          // overlay W3b after gemm1
    const bool big = (ws_size >= WS_BIG);
    unsigned short* W2b = big ? (unsigned short*)(ws + W2B_OFF)
                              : W1b;            // mid tier: overlay after gemm1

    gate_kernel<<<T_TOKENS, 64, 0, stream>>>(x, Wg, top_idx, top_w, Xb);
    route_cvt_kernel<<<2049, 256, 0, stream>>>(
        top_idx, top_w, hdr, slot_token, slot_weight,
        W1, W3, big ? W2 : nullptr, W1b, W3b, W2b);
    gemm1_p<<<dim3(D_MLP / BN, T_TOKENS / BM, NUM_EXPERTS), 256, 0, stream>>>(
        Xb, W1b, W3b, hdr, slot_token, H);
    if (!big) cvt_kernel<<<2048, 256, 0, stream>>>(W2, W2b, NW8);
    gemm2_p<<<dim3(D_MODEL / BN, T_TOKENS / BM, NUM_EXPERTS), 256, 0, stream>>>(
        H, W2b, hdr, Y);
    combine_kernel<<<T_TOKENS, 256, 0, stream>>>(Y, top_idx, top_w, out);
  } else {
    gate_kernel<<<T_TOKENS, 64, 0, stream>>>(x, Wg, top_idx, top_w, nullptr);
    route_cvt_kernel<<<1, 256, 0, stream>>>(
        top_idx, top_w, hdr, slot_token, slot_weight,
        nullptr, nullptr, nullptr, nullptr, nullptr, nullptr);
    zero_kernel<<<(out_size / 4 + 255) / 256, 256, 0, stream>>>((float4*)d_out, out_size / 4);
    gemm1_kernel<<<dim3(D_MLP / BN, T_TOKENS / BM, NUM_EXPERTS), 256, 0, stream>>>(
        x, W1, W3, hdr, slot_token, H);
    gemm2_kernel<<<dim3(D_MODEL / BN, T_TOKENS / BM, NUM_EXPERTS), 256, 0, stream>>>(
        H, W2, hdr, slot_token, slot_weight, out);
  }
}